// Round 9
// baseline (106.345 us; speedup 1.0000x reference)
//
#include <hip/hip_runtime.h>

#define N_PARTS 62
#define M_SAMP  512
#define D_DIM   256
#define MARGIN  0.2f
#define ROWS    (N_PARTS * M_SAMP)   // 31744
#define PART_ELEMS (M_SAMP * D_DIM)  // 131072 bf16 per part

typedef unsigned short ushort_t;
typedef __attribute__((ext_vector_type(8))) short bf16x8;   // 8 bf16 = 4 VGPRs
typedef __attribute__((ext_vector_type(4))) float f32x4;

__device__ __forceinline__ ushort_t bf16_rne(float f) {
    unsigned u = __float_as_uint(f);
    unsigned r = u + 0x7fffu + ((u >> 16) & 1u);
    return (ushort_t)(r >> 16);
}

// K1: fp32 -> bf16 (RNE), per-row sum-of-squares of the ROUNDED values,
// zero-init d_out. FRAGMENT-MAJOR output: per (part, chunk c=k>>5, row-group
// g=row>>4) a contiguous 1 KB frag block; lane l of the consuming wave reads
//   F[g*16 + (l&15)][c*32 + (l>>4)*8 .. +7]     at  base + l*16 B.
// Store coalescing: lane pair (2j,2j+1) covers k=8j..8j+7 = one 16 B
// frag-lane slice -> combine via shuffle, even lane stores uint4.
__global__ __launch_bounds__(256) void prep_kernel(const float* __restrict__ feat,
                                                   ushort_t* __restrict__ Fb,
                                                   float* __restrict__ sq,
                                                   float* __restrict__ out) {
    const int gid  = blockIdx.x * 256 + threadIdx.x;
    const int lane = threadIdx.x & 63;
    const int row  = gid >> 6;                    // one wave per row
    const int part = row >> 9, rp = row & 511;
    const float4 v = ((const float4*)(feat + (size_t)row * D_DIM))[lane];
    ushort4 us;
    us.x = bf16_rne(v.x); us.y = bf16_rne(v.y);
    us.z = bf16_rne(v.z); us.w = bf16_rne(v.w);
    const float fx = __uint_as_float((unsigned)us.x << 16);
    const float fy = __uint_as_float((unsigned)us.y << 16);
    const float fz = __uint_as_float((unsigned)us.z << 16);
    const float fw = __uint_as_float((unsigned)us.w << 16);
    // pair j = lane>>1 covers k = 8j..8j+7: c = lane>>3, q = (lane>>1)&3
    uint2 pk;
    pk.x = (unsigned)us.x | ((unsigned)us.y << 16);
    pk.y = (unsigned)us.z | ((unsigned)us.w << 16);
    const unsigned ox = __shfl_xor(pk.x, 1);
    const unsigned oy = __shfl_xor(pk.y, 1);
    if ((lane & 1) == 0) {
        const int c  = lane >> 3;
        const int q  = (lane >> 1) & 3;
        const int g  = rp >> 4;
        const int fl = (rp & 15) | (q << 4);      // frag lane
        uint4 w4; w4.x = pk.x; w4.y = pk.y; w4.z = ox; w4.w = oy;
        *(uint4*)(Fb + (size_t)part * PART_ELEMS + ((size_t)(c * 32 + g) * 512)
                  + fl * 8) = w4;
    }
    float ssum = fx * fx + fy * fy + fz * fz + fw * fw;
    #pragma unroll
    for (int off = 32; off > 0; off >>= 1) ssum += __shfl_xor(ssum, off);
    if (lane == 0) sq[row] = ssum;
    if (gid < 2 * N_PARTS) out[gid] = 0.0f;
}

// K2: LDS-free MFMA K-loop with EXPLICIT VGPR DOUBLE-BUFFER: chunk c+1's 8
// frags are loaded (global->VGPR, lane-contiguous) before chunk c's MFMAs, so
// up to 8 loads stay in flight across the whole sweep (fine-grained vmcnt).
// Grid 512 (id = rt*64 + n -> XCD = n%8: all 8 row-blocks of a part share one
// XCD's L2). Block = 512 thr / 8 waves = 64 rows x all 512 cols.
__global__ __launch_bounds__(512, 4) void fused_triplet_kernel(const ushort_t* __restrict__ Fb,
                                                               const float* __restrict__ sq,
                                                               float* __restrict__ out) {
    const int id = blockIdx.x;
    const int n  = id & 63;          // part (XCD affinity: id%8 == n%8)
    const int rt = id >> 6;          // row-slab
    if (n >= N_PARTS) return;
    const int r0 = rt * 64;
    const int tid = threadIdx.x;
    const int wave = tid >> 6, lane = tid & 63;
    const ushort_t* F = Fb + (size_t)n * PART_ELEMS;
    const float* SQ = sq + n * M_SAMP;

    __shared__ float mrg[8][64][3];   // per-wave row stats (6 KB only)

    f32x4 acc[4][4] = {};
    bf16x8 af[2][4], bf[2][4];

    const ushort_t* aptr = F + (size_t)(rt * 4) * 512 + lane * 8;     // A frags
    const ushort_t* bptr = F + (size_t)(wave * 4) * 512 + lane * 8;   // B frags

    #pragma unroll
    for (int i = 0; i < 4; ++i) {
        af[0][i] = *(const bf16x8*)(aptr + (size_t)i * 512);
        bf[0][i] = *(const bf16x8*)(bptr + (size_t)i * 512);
    }
    #pragma unroll
    for (int c = 0; c < 8; ++c) {
        const int cur = c & 1, nxt = cur ^ 1;
        if (c < 7) {   // prefetch chunk c+1 into the other register bank
            const size_t off = (size_t)(c + 1) * (32 * 512);
            #pragma unroll
            for (int i = 0; i < 4; ++i) {
                af[nxt][i] = *(const bf16x8*)(aptr + off + (size_t)i * 512);
                bf[nxt][i] = *(const bf16x8*)(bptr + off + (size_t)i * 512);
            }
        }
        #pragma unroll
        for (int mi = 0; mi < 4; ++mi)
            #pragma unroll
            for (int ni = 0; ni < 4; ++ni)
                acc[mi][ni] = __builtin_amdgcn_mfma_f32_16x16x32_bf16(
                    af[cur][mi], bf[cur][ni], acc[mi][ni], 0, 0, 0);
    }

    // Epilogue: dist + hard-pos/neg + row sums. C/D layout: col=lane&15,
    // row=(lane>>4)*4+reg (verified across R2-R8 passes).
    float sqc[4];
    #pragma unroll
    for (int ni = 0; ni < 4; ++ni)
        sqc[ni] = SQ[wave * 64 + ni * 16 + (lane & 15)];
    #pragma unroll
    for (int mi = 0; mi < 4; ++mi) {
        #pragma unroll
        for (int p = 0; p < 4; ++p) {
            const int rl = mi * 16 + (lane >> 4) * 4 + p;   // block-local row
            const int R  = r0 + rl;                          // part-local row
            const float sr = SQ[R];
            float ds = 0.f, hp = 0.f, hn = 1e30f;
            #pragma unroll
            for (int ni = 0; ni < 4; ++ni) {
                const int C = wave * 64 + ni * 16 + (lane & 15);
                const float d2 = sr + sqc[ni] - 2.f * acc[mi][ni][p];
                const float d  = sqrtf(fmaxf(d2, 0.f));
                ds += d;
                if ((R >> 3) == (C >> 3)) hp = fmaxf(hp, d);   // label = m>>3
                else                      hn = fminf(hn, d);
            }
            #pragma unroll
            for (int off = 1; off < 16; off <<= 1) {
                ds += __shfl_xor(ds, off);
                hp = fmaxf(hp, __shfl_xor(hp, off));
                hn = fminf(hn, __shfl_xor(hn, off));
            }
            if ((lane & 15) == 0) {
                mrg[wave][rl][0] = hp;
                mrg[wave][rl][1] = hn;
                mrg[wave][rl][2] = ds;
            }
        }
    }
    __syncthreads();
    if (tid < 64) {   // one lane per row: merge the 8 col-slabs + final sum
        float hp = 0.f, hn = 1e30f, bd = 0.f;
        #pragma unroll
        for (int w = 0; w < 8; ++w) {
            hp = fmaxf(hp, mrg[w][tid][0]);
            hn = fminf(hn, mrg[w][tid][1]);
            bd += mrg[w][tid][2];
        }
        float bl = fmaxf(MARGIN + hp - hn, 0.f);
        #pragma unroll
        for (int off = 32; off > 0; off >>= 1) {
            bl += __shfl_xor(bl, off);
            bd += __shfl_xor(bd, off);
        }
        if (lane == 0) {
            atomicAdd(&out[n],           bl * (1.0f / 512.0f));
            atomicAdd(&out[N_PARTS + n], bd * (1.0f / (512.0f * 512.0f)));
        }
    }
}

extern "C" void kernel_launch(void* const* d_in, const int* in_sizes, int n_in,
                              void* d_out, int out_size, void* d_ws, size_t ws_size,
                              hipStream_t stream) {
    const float* feat = (const float*)d_in[0];    // [62, 512, 256] fp32
    float* out = (float*)d_out;                   // [124]

    ushort_t* Fb = (ushort_t*)d_ws;                                   // frag-major bf16
    float* sq    = (float*)((char*)d_ws + (size_t)ROWS * D_DIM * 2);  // row sum-of-squares

    prep_kernel<<<dim3(ROWS / 4), 256, 0, stream>>>(feat, Fb, sq, out);
    fused_triplet_kernel<<<dim3(512), 512, 0, stream>>>(Fb, sq, out);
}

// Round 10
// 92.920 us; speedup vs baseline: 1.1445x; 1.1445x over previous
//
#include <hip/hip_runtime.h>

#define N_PARTS 62
#define M_SAMP  512
#define D_DIM   256
#define MARGIN  0.2f
#define ROWS    (N_PARTS * M_SAMP)   // 31744
#define PART_ELEMS (M_SAMP * D_DIM)  // 131072 bf16 per part

typedef unsigned short ushort_t;
typedef __attribute__((ext_vector_type(8))) short bf16x8;   // 8 bf16 = 4 VGPRs
typedef __attribute__((ext_vector_type(4))) float f32x4;

__device__ __forceinline__ ushort_t bf16_rne(float f) {
    unsigned u = __float_as_uint(f);
    unsigned r = u + 0x7fffu + ((u >> 16) & 1u);
    return (ushort_t)(r >> 16);
}

// K1 (identical to R8): fp32 -> bf16 (RNE), per-row sum-of-squares of the
// ROUNDED values, zero-init d_out. FRAGMENT-MAJOR output: per (part, chunk
// c=k>>5, row-group g=row>>4) a contiguous 1 KB frag block; lane l of the
// consuming wave reads F[g*16+(l&15)][c*32+(l>>4)*8..+7] at base + l*16 B.
__global__ __launch_bounds__(256) void prep_kernel(const float* __restrict__ feat,
                                                   ushort_t* __restrict__ Fb,
                                                   float* __restrict__ sq,
                                                   float* __restrict__ out) {
    const int gid  = blockIdx.x * 256 + threadIdx.x;
    const int lane = threadIdx.x & 63;
    const int row  = gid >> 6;                    // one wave per row
    const int part = row >> 9, rp = row & 511;
    const float4 v = ((const float4*)(feat + (size_t)row * D_DIM))[lane];
    ushort4 us;
    us.x = bf16_rne(v.x); us.y = bf16_rne(v.y);
    us.z = bf16_rne(v.z); us.w = bf16_rne(v.w);
    const float fx = __uint_as_float((unsigned)us.x << 16);
    const float fy = __uint_as_float((unsigned)us.y << 16);
    const float fz = __uint_as_float((unsigned)us.z << 16);
    const float fw = __uint_as_float((unsigned)us.w << 16);
    // lane covers k = lane*4 .. +3: c = lane>>3, quad = (lane>>1)&3
    const int c  = lane >> 3;
    const int q  = (lane >> 1) & 3;
    const int g  = rp >> 4;
    const int fl = (rp & 15) | (q << 4);          // frag lane
    *(ushort4*)(Fb + (size_t)part * PART_ELEMS + ((size_t)(c * 32 + g) * 512)
                + fl * 8 + (lane & 1) * 4) = us;
    float ssum = fx * fx + fy * fy + fz * fz + fw * fw;
    #pragma unroll
    for (int off = 32; off > 0; off >>= 1) ssum += __shfl_xor(ssum, off);
    if (lane == 0) sq[row] = ssum;
    if (gid < 2 * N_PARTS) out[gid] = 0.0f;
}

// K2: TRANSPOSED-REDUCTION fused kernel. dist is symmetric, so per-COLUMN
// stats == per-row stats. Block = (part n, col-slab ct: 64 cols); wave w owns
// rows w*64..+63 x the slab's 64 cols (acc[4][4]). Each lane folds hp/hn/ds
// over its 16 REGISTER (mi,p) values -> the 16-lane butterflies disappear
// (192 shuffles -> 24 per thread). K-loop/frag layout identical to R8.
__global__ __launch_bounds__(512, 4) void fused_triplet_kernel(const ushort_t* __restrict__ Fb,
                                                               const float* __restrict__ sq,
                                                               float* __restrict__ out) {
    const int id = blockIdx.x;
    const int n  = id & 63;          // part (XCD affinity: id%8 == n%8)
    const int ct = id >> 6;          // col-slab (64 cols)
    if (n >= N_PARTS) return;
    const int tid = threadIdx.x;
    const int wave = tid >> 6, lane = tid & 63;
    const ushort_t* F = Fb + (size_t)n * PART_ELEMS;
    const float* SQ = sq + n * M_SAMP;

    __shared__ float mrg[8][64][3];   // [wave][slab-local col][hp,hn,ds]

    f32x4 acc[4][4] = {};

    const ushort_t* aptr = F + (size_t)(wave * 4) * 512 + lane * 8;   // A: rows w*64..
    const ushort_t* bptr = F + (size_t)(ct * 4) * 512 + lane * 8;     // B: slab cols

    #pragma unroll
    for (int c = 0; c < 8; ++c) {
        const size_t off = (size_t)c * (32 * 512);
        bf16x8 af[4], bf[4];
        #pragma unroll
        for (int i = 0; i < 4; ++i) {
            af[i] = *(const bf16x8*)(aptr + off + (size_t)i * 512);
            bf[i] = *(const bf16x8*)(bptr + off + (size_t)i * 512);
        }
        #pragma unroll
        for (int mi = 0; mi < 4; ++mi)
            #pragma unroll
            for (int ni = 0; ni < 4; ++ni)
                acc[mi][ni] = __builtin_amdgcn_mfma_f32_16x16x32_bf16(
                    af[mi], bf[ni], acc[mi][ni], 0, 0, 0);
    }

    // Epilogue. C/D layout: col = lane&15, row = (lane>>4)*4 + reg (verified
    // R2-R9). Per lane: 4 cols (ni), 16 rows (mi,p) in REGISTERS -> fold over
    // registers, no shuffles; then 2 cross-quad butterfly steps only.
    float sqr[4][4];
    #pragma unroll
    for (int mi = 0; mi < 4; ++mi)
        #pragma unroll
        for (int p = 0; p < 4; ++p)
            sqr[mi][p] = SQ[wave * 64 + mi * 16 + (lane >> 4) * 4 + p];

    #pragma unroll
    for (int ni = 0; ni < 4; ++ni) {
        const int C = ct * 64 + ni * 16 + (lane & 15);   // part-local col
        const float sc = SQ[C];
        const int Cg = C >> 3;                            // label = m>>3
        float ds = 0.f, hp = 0.f, hn = 1e30f;
        #pragma unroll
        for (int mi = 0; mi < 4; ++mi) {
            #pragma unroll
            for (int p = 0; p < 4; ++p) {
                const int R = wave * 64 + mi * 16 + (lane >> 4) * 4 + p;
                const float d2 = sqr[mi][p] + sc - 2.f * acc[mi][ni][p];
                const float d  = __builtin_amdgcn_sqrtf(fmaxf(d2, 0.f));
                ds += d;
                if ((R >> 3) == Cg) hp = fmaxf(hp, d);
                else                hn = fminf(hn, d);
            }
        }
        // combine the 4 quads (same col, disjoint row subsets): lanes l^16, l^32
        #pragma unroll
        for (int off = 16; off < 64; off <<= 1) {
            ds += __shfl_xor(ds, off);
            hp = fmaxf(hp, __shfl_xor(hp, off));
            hn = fminf(hn, __shfl_xor(hn, off));
        }
        if (lane < 16) {
            mrg[wave][ni * 16 + lane][0] = hp;
            mrg[wave][ni * 16 + lane][1] = hn;
            mrg[wave][ni * 16 + lane][2] = ds;
        }
    }
    __syncthreads();
    if (tid < 64) {   // col tid of the slab: merge 8 row-strips + final sum
        float hp = 0.f, hn = 1e30f, bd = 0.f;
        #pragma unroll
        for (int w = 0; w < 8; ++w) {
            hp = fmaxf(hp, mrg[w][tid][0]);
            hn = fminf(hn, mrg[w][tid][1]);
            bd += mrg[w][tid][2];
        }
        float bl = fmaxf(MARGIN + hp - hn, 0.f);
        #pragma unroll
        for (int off = 32; off > 0; off >>= 1) {
            bl += __shfl_xor(bl, off);
            bd += __shfl_xor(bd, off);
        }
        if (lane == 0) {
            atomicAdd(&out[n],           bl * (1.0f / 512.0f));
            atomicAdd(&out[N_PARTS + n], bd * (1.0f / (512.0f * 512.0f)));
        }
    }
}

extern "C" void kernel_launch(void* const* d_in, const int* in_sizes, int n_in,
                              void* d_out, int out_size, void* d_ws, size_t ws_size,
                              hipStream_t stream) {
    const float* feat = (const float*)d_in[0];    // [62, 512, 256] fp32
    float* out = (float*)d_out;                   // [124]

    ushort_t* Fb = (ushort_t*)d_ws;                                   // frag-major bf16
    float* sq    = (float*)((char*)d_ws + (size_t)ROWS * D_DIM * 2);  // row sum-of-squares

    prep_kernel<<<dim3(ROWS / 4), 256, 0, stream>>>(feat, Fb, sq, out);
    fused_triplet_kernel<<<dim3(512), 512, 0, stream>>>(Fb, sq, out);
}